// Round 3
// baseline (250.269 us; speedup 1.0000x reference)
//
#include <hip/hip_runtime.h>
#include <math.h>

// Problem constants (from reference): feature_map [16,64,224,224], points [16,1024,2]
#define BB   16
#define HH   224
#define WW   224
#define NPTS 1024
#define KS   23      // int(224*0.1)=22 -> +1 = 23
#define HALF 11
#define SIGMA2_2 18.0f  // 2*sigma^2, sigma=3

#define TR   8            // output rows per block (fused conv)
#define ER   (TR + KS - 1)  // 30 extended rows needed per tile
#define NTIL (HH / TR)    // 28 row-tiles per image

// Scatter point counts into [B,H,W] grid (grid pre-zeroed by memset).
__global__ void scatter_counts(const float* __restrict__ pts, float* __restrict__ cnt) {
    int idx = blockIdx.x * blockDim.x + threadIdx.x;
    if (idx >= BB * NPTS) return;
    int b = idx / NPTS;
    float px = pts[2 * idx + 0];
    float py = pts[2 * idx + 1];
    int x = (int)(px * (float)WW);  // trunc of nonneg == astype(int32)
    int y = (int)(py * (float)HH);
    if ((unsigned)x >= WW || (unsigned)y >= HH) return;
    atomicAdd(&cnt[(b * HH + y) * WW + x], 1.0f);
}

// Fused separable 23-tap gaussian blur: cnt[B,H,W] -> out[B,H,W], zero-padded
// boundaries (== reference's padded-scatter-then-crop semantics).
// One block = 8 output rows of one image. LDS: 30x224 cnt tile -> hconv in
// LDS -> vconv -> global store. OOB rows are zeroed in LDS, so vconv needs no
// bounds checks. All LDS patterns are lane-consecutive (2-way aliasing, free).
__global__ __launch_bounds__(256) void fused_blur(const float* __restrict__ cnt,
                                                  float* __restrict__ out) {
    __shared__ float s_cnt[ER * WW];   // 30*224*4 = 26.25 KB
    __shared__ float s_h[ER * WW];     // 26.25 KB
    __shared__ float s_w[KS];

    int blk = blockIdx.x;
    int b = blk / NTIL;
    int r0 = (blk % NTIL) * TR;        // first output row of this tile

    // Weights once per block (proven numerics: fp32 expf, L1-normalized).
    if (threadIdx.x == 0) {
        float s = 0.0f;
        float v[KS];
#pragma unroll
        for (int t = 0; t < KS; ++t) {
            float ax = (float)(t - HALF);
            v[t] = __expf(-(ax * ax) / SIGMA2_2);
            s += v[t];
        }
        float inv = 1.0f / s;
#pragma unroll
        for (int t = 0; t < KS; ++t) s_w[t] = v[t] * inv;
    }

    // Stage extended cnt tile (rows r0-11 .. r0+18), float4, zero OOB rows.
    const float* src = cnt + (size_t)b * HH * WW;
    for (int q = threadIdx.x; q < ER * (WW / 4); q += 256) {
        int r = q / (WW / 4);
        int c = (q % (WW / 4)) * 4;
        int gr = r0 - HALF + r;
        float4 v = make_float4(0.f, 0.f, 0.f, 0.f);
        if ((unsigned)gr < (unsigned)HH) v = *(const float4*)(src + (size_t)gr * WW + c);
        *(float4*)(&s_cnt[r * WW + c]) = v;
    }
    __syncthreads();

    // Cache weights into registers (constant-index -> stays in VGPRs).
    float w[KS];
#pragma unroll
    for (int t = 0; t < KS; ++t) w[t] = s_w[t];

    // Horizontal pass: all 30 rows.
    for (int q = threadIdx.x; q < ER * WW; q += 256) {
        int j = q % WW;
        const float* row = &s_cnt[q - j];
        float acc = 0.0f;
#pragma unroll
        for (int t = 0; t < KS; ++t) {
            int x = j + t - HALF;
            float v = ((unsigned)x < (unsigned)WW) ? row[x] : 0.0f;
            acc = fmaf(v, w[t], acc);
        }
        s_h[q] = acc;
    }
    __syncthreads();

    // Vertical pass: 8 output rows. OOB rows already zero in s_h.
    float* dst = out + ((size_t)b * HH + r0) * WW;
    for (int q = threadIdx.x; q < TR * WW; q += 256) {
        int j = q % WW;
        int r = q / WW;                 // local output row; s_h row r..r+22
        float acc = 0.0f;
#pragma unroll
        for (int t = 0; t < KS; ++t)
            acc = fmaf(s_h[(r + t) * WW + j], w[t], acc);
        dst[q] = acc;
    }
}

extern "C" void kernel_launch(void* const* d_in, const int* in_sizes, int n_in,
                              void* d_out, int out_size, void* d_ws, size_t ws_size,
                              hipStream_t stream) {
    // d_in[0] = feature_map (values unused, only shape matters)
    const float* pts = (const float*)d_in[1];
    float* out = (float*)d_out;

    const int PIX = BB * HH * WW;  // 802,816
    float* cnt = (float*)d_ws;     // [B,H,W] — only ws user now (3.2 MB)

    // ws is re-poisoned to 0xAA each call — zero the count grid ourselves.
    hipMemsetAsync(cnt, 0, (size_t)PIX * sizeof(float), stream);

    scatter_counts<<<(BB * NPTS + 255) / 256, 256, 0, stream>>>(pts, cnt);
    fused_blur<<<BB * NTIL, 256, 0, stream>>>(cnt, out);
}